// Round 9
// baseline (1810.673 us; speedup 1.0000x reference)
//
#include <hip/hip_runtime.h>

#define D    64
#define K    512
#define QTOT (8 * 16384)
#define THR  0.06f

typedef __attribute__((ext_vector_type(8))) short short8;   // 8 bf16 payloads (4 VGPRs)
typedef __attribute__((ext_vector_type(4))) short short4v;  // 4 bf16 payloads (8 B)
typedef __attribute__((ext_vector_type(4))) float f32x4;

__device__ __forceinline__ unsigned short f2bf(float f) {   // fp32 -> bf16 (RNE)
    unsigned u = __builtin_bit_cast(unsigned, f);
    u = u + 0x7FFFu + ((u >> 16) & 1u);
    return (unsigned short)(u >> 16);
}
__device__ __forceinline__ float bf2f(unsigned short h) {
    unsigned u = ((unsigned)h) << 16;
    return __builtin_bit_cast(float, u);
}

// ---- prep (proven round 8): esq + bf16 split of (-2*codebook) ----
__global__ __launch_bounds__(512) void prep2_kernel(const float* __restrict__ cb,
        float* __restrict__ esq, unsigned short* __restrict__ eh2,
        unsigned short* __restrict__ el2) {
    const int tid = threadIdx.x;
    const float4* cbv4 = (const float4*)cb;
    for (int c = tid; c < (K * D) / 4; c += 512) {
        float4 v = cbv4[c];
        float vv[4] = {v.x, v.y, v.z, v.w};
        short4v hi, lo;
        #pragma unroll
        for (int j = 0; j < 4; ++j) {
            unsigned short hb = f2bf(vv[j]);
            float hf = bf2f(hb);
            unsigned short lb = f2bf(vv[j] - hf);
            hi[j] = (short)f2bf(-2.0f * hf);          // exact power-of-2 scaling
            lo[j] = (short)f2bf(-2.0f * bf2f(lb));
        }
        ((short4v*)eh2)[c] = hi;
        ((short4v*)el2)[c] = lo;
    }
    const float4* rp = (const float4*)(cb + (size_t)tid * D);
    float s = 0.f;
    #pragma unroll
    for (int i = 0; i < 16; ++i) {
        float4 v = rp[i];
        s = fmaf(v.x, v.x, s); s = fmaf(v.y, v.y, s);
        s = fmaf(v.z, v.z, s); s = fmaf(v.w, v.w, s);
    }
    esq[tid] = s;
}

// ---- main: round-7 structure (1024 thr = 16 waves, 4/SIMD, LDS codebook),
// esq+128 folded into MFMA C-init, packed-index min-track (halved VALU) ----
__global__ __launch_bounds__(1024) void vq_mfma5(
        const float* __restrict__ x, const float* __restrict__ cb,
        const float* __restrict__ g_esq, const unsigned short* __restrict__ eh2,
        const unsigned short* __restrict__ el2, float* __restrict__ out) {

    __shared__ unsigned short s_e[2][K * D];   // (-2*hi)/(-2*lo) codebook, XOR-swizzled
    __shared__ float s_esq[K];                 // raw esq (rescan authority)
    __shared__ float s_esqb[K];                // esq + 128 (MFMA C-init; dd+128 in (0,512))

    const int tid  = threadIdx.x;
    const int lane = tid & 63;
    const int qrow = lane & 15;                 // query col of C / code row of A
    const int kg   = lane >> 4;
    const int kgbase = kg * 4;
    const int wv   = __builtin_amdgcn_readfirstlane(tid >> 6);   // 0..15
    const int qw   = blockIdx.x * 512 + wv * 32;   // wave's first query (qt=2 x 16)

    // stage pre-split (-2x) codebook into swizzled LDS (4 iters/thread)
    for (int c = tid; c < (K * D) / 8; c += 1024) {
        short8 hv = ((const short8*)eh2)[c];
        short8 lv = ((const short8*)el2)[c];
        int byteoff = c * 16;
        int row     = byteoff >> 7;             // 128 B per code row
        int addr    = byteoff ^ ((row & 7) << 4);
        *(short8*)((char*)s_e[0] + addr) = hv;
        *(short8*)((char*)s_e[1] + addr) = lv;
    }
    if (tid < K) {
        float e = g_esq[tid];
        s_esq[tid]  = e;
        s_esqb[tid] = e + 128.0f;
    }
    __syncthreads();

    // B-fragments: lane slot (kg, j) holds x[query][h*32 + kg*8 + j], hi/lo split.
    short8 xh[2][2], xl[2][2];
    #pragma unroll
    for (int qt = 0; qt < 2; ++qt) {
        #pragma unroll
        for (int h = 0; h < 2; ++h) {
            const float* p = x + (size_t)(qw + qt * 16 + qrow) * D + h * 32 + kg * 8;
            float4 v0 = *(const float4*)p;
            float4 v1 = *(const float4*)(p + 4);
            float vv[8] = {v0.x, v0.y, v0.z, v0.w, v1.x, v1.y, v1.z, v1.w};
            short8 th, tl;
            #pragma unroll
            for (int j = 0; j < 8; ++j) {
                unsigned short hb = f2bf(vv[j]);
                th[j] = (short)hb;
                tl[j] = (short)f2bf(vv[j] - bf2f(hb));
            }
            xh[qt][h] = th;
            xl[qt][h] = tl;
        }
    }

    // packed (value|index) min-tracking: dd+128 > 0 so float-min == lex-min
    float m1[2], m2[2];
    #pragma unroll
    for (int qt = 0; qt < 2; ++qt) { m1[qt] = 3.4e38f; m2[qt] = 3.4e38f; }

    for (int t = 0; t < 32; ++t) {
        const int row  = t * 16 + qrow;         // A-operand code row
        const int swz  = (row & 7) << 4;
        const int off0 = row * 128 + kg * 16;
        short8 eh0 = *(const short8*)((const char*)s_e[0] + ((off0     ) ^ swz));
        short8 eh1 = *(const short8*)((const char*)s_e[0] + ((off0 + 64) ^ swz));
        short8 el0 = *(const short8*)((const char*)s_e[1] + ((off0     ) ^ swz));
        short8 el1 = *(const short8*)((const char*)s_e[1] + ((off0 + 64) ^ swz));
        f32x4 eqb = *(const f32x4*)(s_esqb + t * 16 + kgbase);

        #pragma unroll
        for (int qt = 0; qt < 2; ++qt) {
            // C-init = esq+128; -2 folded into codebook -> acc == d2proxy+128
            f32x4 acc = eqb;
            acc = __builtin_amdgcn_mfma_f32_16x16x32_bf16(eh0, xh[qt][0], acc, 0, 0, 0);
            acc = __builtin_amdgcn_mfma_f32_16x16x32_bf16(eh1, xh[qt][1], acc, 0, 0, 0);
            acc = __builtin_amdgcn_mfma_f32_16x16x32_bf16(eh0, xl[qt][0], acc, 0, 0, 0);
            acc = __builtin_amdgcn_mfma_f32_16x16x32_bf16(eh1, xl[qt][1], acc, 0, 0, 0);
            acc = __builtin_amdgcn_mfma_f32_16x16x32_bf16(el0, xh[qt][0], acc, 0, 0, 0);
            acc = __builtin_amdgcn_mfma_f32_16x16x32_bf16(el1, xh[qt][1], acc, 0, 0, 0);
            #pragma unroll
            for (int r = 0; r < 4; ++r) {
                // pack 9-bit code index into low mantissa bits (perturb <= 0.016,
                // covered by THR); positive values -> min is lex (value, index)
                unsigned ub = __builtin_bit_cast(unsigned, acc[r]);
                float pv = __builtin_bit_cast(float,
                            (ub & 0xFFFFFE00u) | (unsigned)((t * 16 + r) | kgbase));
                m2[qt] = fminf(m2[qt], fmaxf(m1[qt], pv));   // top-2, 2 ops
                m1[qt] = fminf(m1[qt], pv);
            }
        }
    }

    // combine packed (m1,m2) across the 4 k-groups holding each query
    #pragma unroll
    for (int qt = 0; qt < 2; ++qt) {
        #pragma unroll
        for (int off = 16; off <= 32; off <<= 1) {
            float om1 = __shfl_xor(m1[qt], off, 64);
            float om2 = __shfl_xor(m2[qt], off, 64);
            m2[qt] = fminf(fminf(m2[qt], om2), fmaxf(m1[qt], om1));
            m1[qt] = fminf(m1[qt], om1);
        }
    }

    int i1[2];
    #pragma unroll
    for (int qt = 0; qt < 2; ++qt)
        i1[qt] = (int)(__builtin_bit_cast(unsigned, m1[qt]) & 0x1FFu);

    // exact fp32 rescan when top-2 gap <= THR (covers packing + bf16x3 error):
    // raw esq + the rounds-2..7-proven chain -> fp32 argmin guaranteed.
    #pragma unroll
    for (int qt = 0; qt < 2; ++qt) {
        bool flag = (m2[qt] - m1[qt]) <= THR;
        unsigned long long mask = __ballot(flag && (lane < 16));
        while (mask) {
            int ql = __ffsll(mask) - 1;
            mask &= mask - 1;
            int qf = qw + qt * 16 + ql;                 // wave-uniform
            const float* xq = x + (size_t)qf * D;
            float bb = 3.4e38f;
            int   bq = 0;
            #pragma unroll 1
            for (int c0 = 0; c0 < 8; ++c0) {
                int kc = lane * 8 + c0;
                const float4* ep = (const float4*)(cb + (size_t)kc * D);
                float a = 0.f;
                #pragma unroll
                for (int i = 0; i < 16; ++i) {
                    float4 e = ep[i];
                    a = fmaf(xq[4 * i + 0], e.x, a);
                    a = fmaf(xq[4 * i + 1], e.y, a);
                    a = fmaf(xq[4 * i + 2], e.z, a);
                    a = fmaf(xq[4 * i + 3], e.w, a);
                }
                float dd = fmaf(-2.f, a, s_esq[kc]);
                if (dd < bb) { bb = dd; bq = kc; }      // ascending kc: first index wins
            }
            #pragma unroll
            for (int off = 1; off < 64; off <<= 1) {    // min-reduce, first-index tie-break
                float ob = __shfl_xor(bb, off, 64);
                int   oq = __shfl_xor(bq, off, 64);
                if (ob < bb || (ob == bb && oq < bq)) { bb = ob; bq = oq; }
            }
            if (qrow == ql) i1[qt] = bq;
        }
    }

    // emit: out[q] = cb[i1]; lane (qrow,kg) writes 64 B of query qrow's row
    #pragma unroll
    for (int qt = 0; qt < 2; ++qt) {
        size_t q = (size_t)(qw + qt * 16 + qrow);
        const float4* src = (const float4*)(cb + (size_t)i1[qt] * D) + kg * 4;
        float4*       dst = (float4*)(out + q * D) + kg * 4;
        #pragma unroll
        for (int s = 0; s < 4; ++s) dst[s] = src[s];
    }
}

// ================= SAFE fallback (no ws): round-4 kernel verbatim (proven) =================
__global__ __launch_bounds__(512) void vq_mfma(
        const float* __restrict__ x, const float* __restrict__ cb,
        float* __restrict__ out) {

    __shared__ unsigned short s_e[2][K * D];
    __shared__ float s_esq[K];

    const int tid  = threadIdx.x;
    const int lane = tid & 63;
    const int qrow = lane & 15;
    const int kg   = lane >> 4;
    const int wv   = __builtin_amdgcn_readfirstlane(tid >> 6);
    const int qw   = blockIdx.x * 512 + wv * 64;

    const float4* cbv4 = (const float4*)cb;
    for (int c = tid; c < (K * D) / 4; c += 512) {
        float4 v = cbv4[c];
        float vv[4] = {v.x, v.y, v.z, v.w};
        short4v hi, lo;
        #pragma unroll
        for (int j = 0; j < 4; ++j) {
            unsigned short hb = f2bf(vv[j]);
            hi[j] = (short)hb;
            lo[j] = (short)f2bf(vv[j] - bf2f(hb));
        }
        int byteoff = c * 8;
        int row     = byteoff >> 7;
        int addr    = byteoff ^ ((row & 7) << 4);
        *(short4v*)((char*)s_e[0] + addr) = hi;
        *(short4v*)((char*)s_e[1] + addr) = lo;
    }
    {
        float s = 0.f;
        #pragma unroll
        for (int d = 0; d < D; ++d) {
            float v = cb[tid * D + d];
            s = fmaf(v, v, s);
        }
        s_esq[tid] = s;
    }
    __syncthreads();

    short8 xh[4][2], xl[4][2];
    #pragma unroll
    for (int qt = 0; qt < 4; ++qt) {
        #pragma unroll
        for (int h = 0; h < 2; ++h) {
            const float* p = x + (size_t)(qw + qt * 16 + qrow) * D + h * 32 + kg * 8;
            float4 v0 = *(const float4*)p;
            float4 v1 = *(const float4*)(p + 4);
            float vv[8] = {v0.x, v0.y, v0.z, v0.w, v1.x, v1.y, v1.z, v1.w};
            short8 th, tl;
            #pragma unroll
            for (int j = 0; j < 8; ++j) {
                unsigned short hb = f2bf(vv[j]);
                th[j] = (short)hb;
                tl[j] = (short)f2bf(vv[j] - bf2f(hb));
            }
            xh[qt][h] = th;
            xl[qt][h] = tl;
        }
    }

    float m1[4], m2[4];
    int   i1[4];
    #pragma unroll
    for (int qt = 0; qt < 4; ++qt) { m1[qt] = 3.4e38f; m2[qt] = 3.4e38f; i1[qt] = 0; }

    const f32x4 zacc = {0.f, 0.f, 0.f, 0.f};

    for (int t = 0; t < 32; ++t) {
        const int row  = t * 16 + qrow;
        const int swz  = (row & 7) << 4;
        const int off0 = row * 128 + kg * 16;
        short8 eh0 = *(const short8*)((const char*)s_e[0] + ((off0     ) ^ swz));
        short8 eh1 = *(const short8*)((const char*)s_e[0] + ((off0 + 64) ^ swz));
        short8 el0 = *(const short8*)((const char*)s_e[1] + ((off0     ) ^ swz));
        short8 el1 = *(const short8*)((const char*)s_e[1] + ((off0 + 64) ^ swz));
        f32x4 eq = *(const f32x4*)(s_esq + t * 16 + kg * 4);

        #pragma unroll
        for (int qt = 0; qt < 4; ++qt) {
            f32x4 acc;
            asm volatile(
                "s_nop 3\n\t"
                "v_mfma_f32_16x16x32_bf16 %0, %1, %5, %9\n\t"
                "v_mfma_f32_16x16x32_bf16 %0, %2, %6, %0\n\t"
                "v_mfma_f32_16x16x32_bf16 %0, %1, %7, %0\n\t"
                "v_mfma_f32_16x16x32_bf16 %0, %2, %8, %0\n\t"
                "v_mfma_f32_16x16x32_bf16 %0, %3, %5, %0\n\t"
                "v_mfma_f32_16x16x32_bf16 %0, %4, %6, %0\n\t"
                "s_nop 7\n\t"
                "s_nop 7"
                : "=&v"(acc)
                : "v"(eh0), "v"(eh1), "v"(el0), "v"(el1),
                  "v"(xh[qt][0]), "v"(xh[qt][1]), "v"(xl[qt][0]), "v"(xl[qt][1]),
                  "v"(zacc));
            #pragma unroll
            for (int r = 0; r < 4; ++r) {
                float dd = fmaf(-2.f, acc[r], eq[r]);
                int   kc = t * 16 + kg * 4 + r;
                bool  lt = dd < m1[qt];
                m2[qt] = lt ? m1[qt] : fminf(m2[qt], dd);
                m1[qt] = lt ? dd : m1[qt];
                i1[qt] = lt ? kc : i1[qt];
            }
        }
    }

    #pragma unroll
    for (int qt = 0; qt < 4; ++qt) {
        #pragma unroll
        for (int off = 16; off <= 32; off <<= 1) {
            float om1 = __shfl_xor(m1[qt], off, 64);
            float om2 = __shfl_xor(m2[qt], off, 64);
            int   oi  = __shfl_xor(i1[qt], off, 64);
            bool  lt  = om1 < m1[qt];
            float loser = lt ? m1[qt] : om1;
            m2[qt] = fminf(fminf(m2[qt], om2), loser);
            m1[qt] = lt ? om1 : m1[qt];
            i1[qt] = lt ? oi  : i1[qt];
        }
    }

    #pragma unroll
    for (int qt = 0; qt < 4; ++qt) {
        bool flag = (m2[qt] - m1[qt]) <= 0.008f;
        unsigned long long mask = __ballot(flag && (lane < 16));
        while (mask) {
            int ql = __ffsll(mask) - 1;
            mask &= mask - 1;
            int qf = qw + qt * 16 + ql;
            const float* xq = x + (size_t)qf * D;
            float bb = 3.4e38f;
            int   bq = 0;
            #pragma unroll 1
            for (int c0 = 0; c0 < 8; ++c0) {
                int kc = lane * 8 + c0;
                const float4* ep = (const float4*)(cb + (size_t)kc * D);
                float a = 0.f;
                #pragma unroll
                for (int i = 0; i < 16; ++i) {
                    float4 e = ep[i];
                    a = fmaf(xq[4 * i + 0], e.x, a);
                    a = fmaf(xq[4 * i + 1], e.y, a);
                    a = fmaf(xq[4 * i + 2], e.z, a);
                    a = fmaf(xq[4 * i + 3], e.w, a);
                }
                float dd = fmaf(-2.f, a, s_esq[kc]);
                if (dd < bb) { bb = dd; bq = kc; }
            }
            #pragma unroll
            for (int off = 1; off < 64; off <<= 1) {
                float ob = __shfl_xor(bb, off, 64);
                int   oq = __shfl_xor(bq, off, 64);
                if (ob < bb || (ob == bb && oq < bq)) { bb = ob; bq = oq; }
            }
            if (qrow == ql) i1[qt] = bq;
        }
    }

    #pragma unroll
    for (int qt = 0; qt < 4; ++qt) {
        size_t q = (size_t)(qw + qt * 16 + qrow);
        const float4* src = (const float4*)(cb + (size_t)i1[qt] * D) + kg * 4;
        float4*       dst = (float4*)(out + q * D) + kg * 4;
        #pragma unroll
        for (int s = 0; s < 4; ++s) dst[s] = src[s];
    }
}

extern "C" void kernel_launch(void* const* d_in, const int* in_sizes, int n_in,
                              void* d_out, int out_size, void* d_ws, size_t ws_size,
                              hipStream_t stream) {
    const float* x   = (const float*)d_in[0];   // [8,16384,64]
    const float* cb  = (const float*)d_in[1];   // [512,64]
    float*       out = (float*)d_out;           // [8,16384,1,64]

    const size_t need = 2048 + (size_t)K * D * 2 * 2;   // esq + eh2 + el2 = 133120 B
    if (ws_size >= need) {
        float*          esq = (float*)d_ws;
        unsigned short* eh2 = (unsigned short*)((char*)d_ws + 2048);
        unsigned short* el2 = (unsigned short*)((char*)d_ws + 2048 + K * D * 2);
        prep2_kernel<<<1, 512, 0, stream>>>(cb, esq, eh2, el2);
        vq_mfma5<<<QTOT / 512, 1024, 0, stream>>>(x, cb, esq, eh2, el2, out);
    } else {
        vq_mfma<<<QTOT / 512, 512, 0, stream>>>(x, cb, out);
    }
}

// Round 10
// 58.918 us; speedup vs baseline: 30.7320x; 30.7320x over previous
//
#include <hip/hip_runtime.h>

#define D    64
#define K    512
#define QTOT (8 * 16384)
#define THR  0.008f

typedef __attribute__((ext_vector_type(8))) short short8;   // 8 bf16 payloads (4 VGPRs)
typedef __attribute__((ext_vector_type(4))) short short4v;  // 4 bf16 payloads (8 B)
typedef __attribute__((ext_vector_type(4))) float f32x4;

__device__ __forceinline__ unsigned short f2bf(float f) {   // fp32 -> bf16 (RNE)
    unsigned u = __builtin_bit_cast(unsigned, f);
    u = u + 0x7FFFu + ((u >> 16) & 1u);
    return (unsigned short)(u >> 16);
}
__device__ __forceinline__ float bf2f(unsigned short h) {
    unsigned u = ((unsigned)h) << 16;
    return __builtin_bit_cast(float, u);
}

// ---- prep (proven round 8): esq + bf16 split of (-2*codebook) ----
__global__ __launch_bounds__(512) void prep2_kernel(const float* __restrict__ cb,
        float* __restrict__ esq, unsigned short* __restrict__ eh2,
        unsigned short* __restrict__ el2) {
    const int tid = threadIdx.x;
    const float4* cbv4 = (const float4*)cb;
    for (int c = tid; c < (K * D) / 4; c += 512) {
        float4 v = cbv4[c];
        float vv[4] = {v.x, v.y, v.z, v.w};
        short4v hi, lo;
        #pragma unroll
        for (int j = 0; j < 4; ++j) {
            unsigned short hb = f2bf(vv[j]);
            float hf = bf2f(hb);
            unsigned short lb = f2bf(vv[j] - hf);
            hi[j] = (short)f2bf(-2.0f * hf);          // exact power-of-2 scaling
            lo[j] = (short)f2bf(-2.0f * bf2f(lb));
        }
        ((short4v*)eh2)[c] = hi;
        ((short4v*)el2)[c] = lo;
    }
    const float4* rp = (const float4*)(cb + (size_t)tid * D);
    float s = 0.f;
    #pragma unroll
    for (int i = 0; i < 16; ++i) {
        float4 v = rp[i];
        s = fmaf(v.x, v.x, s); s = fmaf(v.y, v.y, s);
        s = fmaf(v.z, v.z, s); s = fmaf(v.w, v.w, s);
    }
    esq[tid] = s;
}

// one k-tile step: C-init = esq tile, single 6-MFMA chain, cndmask min-track
__device__ __forceinline__ void vq_step(
        const short8& eh0, const short8& eh1, const short8& el0, const short8& el1,
        const f32x4& eqv, const short8 xh[2][2], const short8 xl[2][2],
        float m1[2], float m2[2], int i1[2], int t, int kg4) {
    #pragma unroll
    for (int qt = 0; qt < 2; ++qt) {
        f32x4 acc = eqv;    // -2 folded into codebook -> acc exits as d2 proxy
        acc = __builtin_amdgcn_mfma_f32_16x16x32_bf16(eh0, xh[qt][0], acc, 0, 0, 0);
        acc = __builtin_amdgcn_mfma_f32_16x16x32_bf16(eh1, xh[qt][1], acc, 0, 0, 0);
        acc = __builtin_amdgcn_mfma_f32_16x16x32_bf16(eh0, xl[qt][0], acc, 0, 0, 0);
        acc = __builtin_amdgcn_mfma_f32_16x16x32_bf16(eh1, xl[qt][1], acc, 0, 0, 0);
        acc = __builtin_amdgcn_mfma_f32_16x16x32_bf16(el0, xh[qt][0], acc, 0, 0, 0);
        acc = __builtin_amdgcn_mfma_f32_16x16x32_bf16(el1, xh[qt][1], acc, 0, 0, 0);
        #pragma unroll
        for (int r = 0; r < 4; ++r) {
            float dd = acc[r];
            int   kc = t * 16 + kg4 + r;
            bool  lt = dd < m1[qt];
            m2[qt] = lt ? m1[qt] : fminf(m2[qt], dd);
            m1[qt] = lt ? dd : m1[qt];
            i1[qt] = lt ? kc : i1[qt];              // strict < => first index wins
        }
    }
}

// ---- main: 1024 thr = 16 waves (4/SIMD), qt=2, LDS-resident (-2x) codebook,
// explicit A/B register double-buffer of the per-t LDS fragments ----
__global__ __launch_bounds__(1024) void vq_mfma6(
        const float* __restrict__ x, const float* __restrict__ cb,
        const float* __restrict__ g_esq, const unsigned short* __restrict__ eh2,
        const unsigned short* __restrict__ el2, float* __restrict__ out) {

    __shared__ unsigned short s_e[2][K * D];   // (-2*hi)/(-2*lo), XOR-swizzled
    __shared__ float s_esq[K];

    const int tid  = threadIdx.x;
    const int lane = tid & 63;
    const int qrow = lane & 15;                 // query col of C / code row of A
    const int kg   = lane >> 4;
    const int kg4  = kg * 4;
    const int wv   = __builtin_amdgcn_readfirstlane(tid >> 6);   // 0..15
    const int qw   = blockIdx.x * 512 + wv * 32;   // wave's first query (qt=2 x 16)

    // stage pre-split (-2x) codebook into swizzled LDS (4 iters/thread)
    for (int c = tid; c < (K * D) / 8; c += 1024) {
        short8 hv = ((const short8*)eh2)[c];
        short8 lv = ((const short8*)el2)[c];
        int byteoff = c * 16;
        int row     = byteoff >> 7;             // 128 B per code row
        int addr    = byteoff ^ ((row & 7) << 4);
        *(short8*)((char*)s_e[0] + addr) = hv;
        *(short8*)((char*)s_e[1] + addr) = lv;
    }
    if (tid < K) s_esq[tid] = g_esq[tid];
    __syncthreads();

    // B-fragments: lane slot (kg, j) holds x[query][h*32 + kg*8 + j], hi/lo split.
    // A-slots use the same (kg, j) -> dim map, so pairing is k-order independent.
    short8 xh[2][2], xl[2][2];
    #pragma unroll
    for (int qt = 0; qt < 2; ++qt) {
        #pragma unroll
        for (int h = 0; h < 2; ++h) {
            const float* p = x + (size_t)(qw + qt * 16 + qrow) * D + h * 32 + kg * 8;
            float4 v0 = *(const float4*)p;
            float4 v1 = *(const float4*)(p + 4);
            float vv[8] = {v0.x, v0.y, v0.z, v0.w, v1.x, v1.y, v1.z, v1.w};
            short8 th, tl;
            #pragma unroll
            for (int j = 0; j < 8; ++j) {
                unsigned short hb = f2bf(vv[j]);
                th[j] = (short)hb;
                tl[j] = (short)f2bf(vv[j] - bf2f(hb));
            }
            xh[qt][h] = th;
            xl[qt][h] = tl;
        }
    }

    float m1[2], m2[2];
    int   i1[2];
    #pragma unroll
    for (int qt = 0; qt < 2; ++qt) { m1[qt] = 3.4e38f; m2[qt] = 3.4e38f; i1[qt] = 0; }

    // fragment loader (swizzled LDS read), t clamped by caller to valid range
    #define LOAD_FRAG(T, E0, E1, L0, L1, EQ)                                         \
        {                                                                            \
            const int row_  = (T) * 16 + qrow;                                       \
            const int swz_  = (row_ & 7) << 4;                                       \
            const int off_  = row_ * 128 + kg * 16;                                  \
            E0 = *(const short8*)((const char*)s_e[0] + ((off_     ) ^ swz_));       \
            E1 = *(const short8*)((const char*)s_e[0] + ((off_ + 64) ^ swz_));       \
            L0 = *(const short8*)((const char*)s_e[1] + ((off_     ) ^ swz_));       \
            L1 = *(const short8*)((const char*)s_e[1] + ((off_ + 64) ^ swz_));       \
            EQ = *(const f32x4*)(s_esq + (T) * 16 + kg4);                            \
        }

    short8 Ah0, Ah1, Al0, Al1, Bh0, Bh1, Bl0, Bl1;
    f32x4  Aeq, Beq;
    LOAD_FRAG(0, Ah0, Ah1, Al0, Al1, Aeq);

    for (int t = 0; t < 32; t += 2) {
        LOAD_FRAG(t + 1, Bh0, Bh1, Bl0, Bl1, Beq);          // prefetch t+1
        vq_step(Ah0, Ah1, Al0, Al1, Aeq, xh, xl, m1, m2, i1, t, kg4);
        LOAD_FRAG((t + 2) & 31, Ah0, Ah1, Al0, Al1, Aeq);   // prefetch t+2 (&31: safe dummy on last)
        vq_step(Bh0, Bh1, Bl0, Bl1, Beq, xh, xl, m1, m2, i1, t + 1, kg4);
    }
    #undef LOAD_FRAG

    // combine (m1,i1,m2) across the 4 k-groups holding each query
    #pragma unroll
    for (int qt = 0; qt < 2; ++qt) {
        #pragma unroll
        for (int off = 16; off <= 32; off <<= 1) {
            float om1 = __shfl_xor(m1[qt], off, 64);
            float om2 = __shfl_xor(m2[qt], off, 64);
            int   oi  = __shfl_xor(i1[qt], off, 64);
            bool  lt  = om1 < m1[qt];
            float loser = lt ? m1[qt] : om1;
            m2[qt] = fminf(fminf(m2[qt], om2), loser);
            m1[qt] = lt ? om1 : m1[qt];
            i1[qt] = lt ? oi  : i1[qt];
        }
    }

    // exact fp32 rescan when top-2 gap <= THR >= 2*(bf16x3 bound): fp32 argmin
    // guaranteed; approx ties (gap 0) also land here -> first-index restored.
    #pragma unroll
    for (int qt = 0; qt < 2; ++qt) {
        bool flag = (m2[qt] - m1[qt]) <= THR;
        unsigned long long mask = __ballot(flag && (lane < 16));
        while (mask) {
            int ql = __ffsll(mask) - 1;
            mask &= mask - 1;
            int qf = qw + qt * 16 + ql;                 // wave-uniform
            const float* xq = x + (size_t)qf * D;
            float bb = 3.4e38f;
            int   bq = 0;
            #pragma unroll 1
            for (int c0 = 0; c0 < 8; ++c0) {
                int kc = lane * 8 + c0;
                const float4* ep = (const float4*)(cb + (size_t)kc * D);
                float a = 0.f;
                #pragma unroll
                for (int i = 0; i < 16; ++i) {
                    float4 e = ep[i];
                    a = fmaf(xq[4 * i + 0], e.x, a);
                    a = fmaf(xq[4 * i + 1], e.y, a);
                    a = fmaf(xq[4 * i + 2], e.z, a);
                    a = fmaf(xq[4 * i + 3], e.w, a);
                }
                float dd = fmaf(-2.f, a, s_esq[kc]);
                if (dd < bb) { bb = dd; bq = kc; }      // ascending kc: first index wins
            }
            #pragma unroll
            for (int off = 1; off < 64; off <<= 1) {    // min-reduce, first-index tie-break
                float ob = __shfl_xor(bb, off, 64);
                int   oq = __shfl_xor(bq, off, 64);
                if (ob < bb || (ob == bb && oq < bq)) { bb = ob; bq = oq; }
            }
            if (qrow == ql) i1[qt] = bq;
        }
    }

    // emit: out[q] = cb[i1]; lane (qrow,kg) writes 64 B of query qrow's row
    #pragma unroll
    for (int qt = 0; qt < 2; ++qt) {
        size_t q = (size_t)(qw + qt * 16 + qrow);
        const float4* src = (const float4*)(cb + (size_t)i1[qt] * D) + kg * 4;
        float4*       dst = (float4*)(out + q * D) + kg * 4;
        #pragma unroll
        for (int s = 0; s < 4; ++s) dst[s] = src[s];
    }
}

// ================= SAFE fallback (no ws): round-4 kernel verbatim (proven) =================
__global__ __launch_bounds__(512) void vq_mfma(
        const float* __restrict__ x, const float* __restrict__ cb,
        float* __restrict__ out) {

    __shared__ unsigned short s_e[2][K * D];
    __shared__ float s_esq[K];

    const int tid  = threadIdx.x;
    const int lane = tid & 63;
    const int qrow = lane & 15;
    const int kg   = lane >> 4;
    const int wv   = __builtin_amdgcn_readfirstlane(tid >> 6);
    const int qw   = blockIdx.x * 512 + wv * 64;

    const float4* cbv4 = (const float4*)cb;
    for (int c = tid; c < (K * D) / 4; c += 512) {
        float4 v = cbv4[c];
        float vv[4] = {v.x, v.y, v.z, v.w};
        short4v hi, lo;
        #pragma unroll
        for (int j = 0; j < 4; ++j) {
            unsigned short hb = f2bf(vv[j]);
            hi[j] = (short)hb;
            lo[j] = (short)f2bf(vv[j] - bf2f(hb));
        }
        int byteoff = c * 8;
        int row     = byteoff >> 7;
        int addr    = byteoff ^ ((row & 7) << 4);
        *(short4v*)((char*)s_e[0] + addr) = hi;
        *(short4v*)((char*)s_e[1] + addr) = lo;
    }
    {
        float s = 0.f;
        #pragma unroll
        for (int d = 0; d < D; ++d) {
            float v = cb[tid * D + d];
            s = fmaf(v, v, s);
        }
        s_esq[tid] = s;
    }
    __syncthreads();

    short8 xh[4][2], xl[4][2];
    #pragma unroll
    for (int qt = 0; qt < 4; ++qt) {
        #pragma unroll
        for (int h = 0; h < 2; ++h) {
            const float* p = x + (size_t)(qw + qt * 16 + qrow) * D + h * 32 + kg * 8;
            float4 v0 = *(const float4*)p;
            float4 v1 = *(const float4*)(p + 4);
            float vv[8] = {v0.x, v0.y, v0.z, v0.w, v1.x, v1.y, v1.z, v1.w};
            short8 th, tl;
            #pragma unroll
            for (int j = 0; j < 8; ++j) {
                unsigned short hb = f2bf(vv[j]);
                th[j] = (short)hb;
                tl[j] = (short)f2bf(vv[j] - bf2f(hb));
            }
            xh[qt][h] = th;
            xl[qt][h] = tl;
        }
    }

    float m1[4], m2[4];
    int   i1[4];
    #pragma unroll
    for (int qt = 0; qt < 4; ++qt) { m1[qt] = 3.4e38f; m2[qt] = 3.4e38f; i1[qt] = 0; }

    const f32x4 zacc = {0.f, 0.f, 0.f, 0.f};

    for (int t = 0; t < 32; ++t) {
        const int row  = t * 16 + qrow;
        const int swz  = (row & 7) << 4;
        const int off0 = row * 128 + kg * 16;
        short8 eh0 = *(const short8*)((const char*)s_e[0] + ((off0     ) ^ swz));
        short8 eh1 = *(const short8*)((const char*)s_e[0] + ((off0 + 64) ^ swz));
        short8 el0 = *(const short8*)((const char*)s_e[1] + ((off0     ) ^ swz));
        short8 el1 = *(const short8*)((const char*)s_e[1] + ((off0 + 64) ^ swz));
        f32x4 eq = *(const f32x4*)(s_esq + t * 16 + kg * 4);

        #pragma unroll
        for (int qt = 0; qt < 4; ++qt) {
            f32x4 acc;
            asm volatile(
                "s_nop 3\n\t"
                "v_mfma_f32_16x16x32_bf16 %0, %1, %5, %9\n\t"
                "v_mfma_f32_16x16x32_bf16 %0, %2, %6, %0\n\t"
                "v_mfma_f32_16x16x32_bf16 %0, %1, %7, %0\n\t"
                "v_mfma_f32_16x16x32_bf16 %0, %2, %8, %0\n\t"
                "v_mfma_f32_16x16x32_bf16 %0, %3, %5, %0\n\t"
                "v_mfma_f32_16x16x32_bf16 %0, %4, %6, %0\n\t"
                "s_nop 7\n\t"
                "s_nop 7"
                : "=&v"(acc)
                : "v"(eh0), "v"(eh1), "v"(el0), "v"(el1),
                  "v"(xh[qt][0]), "v"(xh[qt][1]), "v"(xl[qt][0]), "v"(xl[qt][1]),
                  "v"(zacc));
            #pragma unroll
            for (int r = 0; r < 4; ++r) {
                float dd = fmaf(-2.f, acc[r], eq[r]);
                int   kc = t * 16 + kg * 4 + r;
                bool  lt = dd < m1[qt];
                m2[qt] = lt ? m1[qt] : fminf(m2[qt], dd);
                m1[qt] = lt ? dd : m1[qt];
                i1[qt] = lt ? kc : i1[qt];
            }
        }
    }

    #pragma unroll
    for (int qt = 0; qt < 4; ++qt) {
        #pragma unroll
        for (int off = 16; off <= 32; off <<= 1) {
            float om1 = __shfl_xor(m1[qt], off, 64);
            float om2 = __shfl_xor(m2[qt], off, 64);
            int   oi  = __shfl_xor(i1[qt], off, 64);
            bool  lt  = om1 < m1[qt];
            float loser = lt ? m1[qt] : om1;
            m2[qt] = fminf(fminf(m2[qt], om2), loser);
            m1[qt] = lt ? om1 : m1[qt];
            i1[qt] = lt ? oi  : i1[qt];
        }
    }

    #pragma unroll
    for (int qt = 0; qt < 4; ++qt) {
        bool flag = (m2[qt] - m1[qt]) <= 0.008f;
        unsigned long long mask = __ballot(flag && (lane < 16));
        while (mask) {
            int ql = __ffsll(mask) - 1;
            mask &= mask - 1;
            int qf = qw + qt * 16 + ql;
            const float* xq = x + (size_t)qf * D;
            float bb = 3.4e38f;
            int   bq = 0;
            #pragma unroll 1
            for (int c0 = 0; c0 < 8; ++c0) {
                int kc = lane * 8 + c0;
                const float4* ep = (const float4*)(cb + (size_t)kc * D);
                float a = 0.f;
                #pragma unroll
                for (int i = 0; i < 16; ++i) {
                    float4 e = ep[i];
                    a = fmaf(xq[4 * i + 0], e.x, a);
                    a = fmaf(xq[4 * i + 1], e.y, a);
                    a = fmaf(xq[4 * i + 2], e.z, a);
                    a = fmaf(xq[4 * i + 3], e.w, a);
                }
                float dd = fmaf(-2.f, a, s_esq[kc]);
                if (dd < bb) { bb = dd; bq = kc; }
            }
            #pragma unroll
            for (int off = 1; off < 64; off <<= 1) {
                float ob = __shfl_xor(bb, off, 64);
                int   oq = __shfl_xor(bq, off, 64);
                if (ob < bb || (ob == bb && oq < bq)) { bb = ob; bq = oq; }
            }
            if (qrow == ql) i1[qt] = bq;
        }
    }

    #pragma unroll
    for (int qt = 0; qt < 4; ++qt) {
        size_t q = (size_t)(qw + qt * 16 + qrow);
        const float4* src = (const float4*)(cb + (size_t)i1[qt] * D) + kg * 4;
        float4*       dst = (float4*)(out + q * D) + kg * 4;
        #pragma unroll
        for (int s = 0; s < 4; ++s) dst[s] = src[s];
    }
}

extern "C" void kernel_launch(void* const* d_in, const int* in_sizes, int n_in,
                              void* d_out, int out_size, void* d_ws, size_t ws_size,
                              hipStream_t stream) {
    const float* x   = (const float*)d_in[0];   // [8,16384,64]
    const float* cb  = (const float*)d_in[1];   // [512,64]
    float*       out = (float*)d_out;           // [8,16384,1,64]

    const size_t need = 2048 + (size_t)K * D * 2 * 2;   // esq + eh2 + el2 = 133120 B
    if (ws_size >= need) {
        float*          esq = (float*)d_ws;
        unsigned short* eh2 = (unsigned short*)((char*)d_ws + 2048);
        unsigned short* el2 = (unsigned short*)((char*)d_ws + 2048 + K * D * 2);
        prep2_kernel<<<1, 512, 0, stream>>>(cb, esq, eh2, el2);
        vq_mfma6<<<QTOT / 512, 1024, 0, stream>>>(x, cb, esq, eh2, el2, out);
    } else {
        vq_mfma<<<QTOT / 512, 512, 0, stream>>>(x, cb, out);
    }
}

// Round 11
// 57.437 us; speedup vs baseline: 31.5247x; 1.0258x over previous
//
#include <hip/hip_runtime.h>

#define D    64
#define K    512
#define QTOT (8 * 16384)
#define THR  0.008f

typedef __attribute__((ext_vector_type(8))) short short8;   // 8 bf16 payloads (4 VGPRs)
typedef __attribute__((ext_vector_type(4))) short short4v;  // 4 bf16 payloads (8 B)
typedef __attribute__((ext_vector_type(4))) float f32x4;

__device__ __forceinline__ unsigned short f2bf(float f) {   // fp32 -> bf16 (RNE)
    unsigned u = __builtin_bit_cast(unsigned, f);
    u = u + 0x7FFFu + ((u >> 16) & 1u);
    return (unsigned short)(u >> 16);
}
__device__ __forceinline__ float bf2f(unsigned short h) {
    unsigned u = ((unsigned)h) << 16;
    return __builtin_bit_cast(float, u);
}

// ---- prep (proven round 8): esq + bf16 split of (-2*codebook) ----
__global__ __launch_bounds__(512) void prep2_kernel(const float* __restrict__ cb,
        float* __restrict__ esq, unsigned short* __restrict__ eh2,
        unsigned short* __restrict__ el2) {
    const int tid = threadIdx.x;
    const float4* cbv4 = (const float4*)cb;
    for (int c = tid; c < (K * D) / 4; c += 512) {
        float4 v = cbv4[c];
        float vv[4] = {v.x, v.y, v.z, v.w};
        short4v hi, lo;
        #pragma unroll
        for (int j = 0; j < 4; ++j) {
            unsigned short hb = f2bf(vv[j]);
            float hf = bf2f(hb);
            unsigned short lb = f2bf(vv[j] - hf);
            hi[j] = (short)f2bf(-2.0f * hf);          // exact power-of-2 scaling
            lo[j] = (short)f2bf(-2.0f * bf2f(lb));
        }
        ((short4v*)eh2)[c] = hi;
        ((short4v*)el2)[c] = lo;
    }
    const float4* rp = (const float4*)(cb + (size_t)tid * D);
    float s = 0.f;
    #pragma unroll
    for (int i = 0; i < 16; ++i) {
        float4 v = rp[i];
        s = fmaf(v.x, v.x, s); s = fmaf(v.y, v.y, s);
        s = fmaf(v.z, v.z, s); s = fmaf(v.w, v.w, s);
    }
    esq[tid] = s;
}

// ---- main: 1024 thr = 16 waves (4/SIMD), qt=2, LDS-resident (-2x) codebook.
// t-loop FULLY unrolled; all LDS addresses are base + compile-time immediate
// (swizzle algebra hoisted: (t*16+qrow)&7 == qrow&7, t*2048 has no XOR bits).
__global__ __launch_bounds__(1024) void vq_mfma7(
        const float* __restrict__ x, const float* __restrict__ cb,
        const float* __restrict__ g_esq, const unsigned short* __restrict__ eh2,
        const unsigned short* __restrict__ el2, float* __restrict__ out) {

    __shared__ unsigned short s_e[2][K * D];   // (-2*hi)/(-2*lo), XOR-swizzled
    __shared__ float s_esq[K];

    const int tid  = threadIdx.x;
    const int lane = tid & 63;
    const int qrow = lane & 15;                 // query col of C / code row of A
    const int kg   = lane >> 4;
    const int kg4  = kg * 4;
    const int wv   = __builtin_amdgcn_readfirstlane(tid >> 6);   // 0..15
    const int qw   = blockIdx.x * 512 + wv * 32;   // wave's first query (qt=2 x 16)

    // stage pre-split (-2x) codebook into swizzled LDS (4 iters/thread)
    for (int c = tid; c < (K * D) / 8; c += 1024) {
        short8 hv = ((const short8*)eh2)[c];
        short8 lv = ((const short8*)el2)[c];
        int byteoff = c * 16;
        int row     = byteoff >> 7;             // 128 B per code row
        int addr    = byteoff ^ ((row & 7) << 4);
        *(short8*)((char*)s_e[0] + addr) = hv;
        *(short8*)((char*)s_e[1] + addr) = lv;
    }
    if (tid < K) s_esq[tid] = g_esq[tid];
    __syncthreads();

    // B-fragments: lane slot (kg, j) holds x[query][h*32 + kg*8 + j], hi/lo split.
    // A-slots use the same (kg, j) -> dim map, so pairing is k-order independent.
    short8 xh[2][2], xl[2][2];
    #pragma unroll
    for (int qt = 0; qt < 2; ++qt) {
        #pragma unroll
        for (int h = 0; h < 2; ++h) {
            const float* p = x + (size_t)(qw + qt * 16 + qrow) * D + h * 32 + kg * 8;
            float4 v0 = *(const float4*)p;
            float4 v1 = *(const float4*)(p + 4);
            float vv[8] = {v0.x, v0.y, v0.z, v0.w, v1.x, v1.y, v1.z, v1.w};
            short8 th, tl;
            #pragma unroll
            for (int j = 0; j < 8; ++j) {
                unsigned short hb = f2bf(vv[j]);
                th[j] = (short)hb;
                tl[j] = (short)f2bf(vv[j] - bf2f(hb));
            }
            xh[qt][h] = th;
            xl[qt][h] = tl;
        }
    }

    float m1[2], m2[2];
    int   i1[2];
    #pragma unroll
    for (int qt = 0; qt < 2; ++qt) { m1[qt] = 3.4e38f; m2[qt] = 3.4e38f; i1[qt] = 0; }

    // loop-invariant swizzled base offsets: (t*16+qrow)&7 == qrow&7, and the
    // per-t term t*2048 shares no bits with the XOR mask (bits 4-6).
    const int swz = (qrow & 7) << 4;
    const int ob  = qrow * 128 + kg * 16;
    const char* ph = (const char*)s_e[0];
    const char* pl = (const char*)s_e[1];
    const int o0 = ob ^ swz;
    const int o1 = (ob + 64) ^ swz;
    const float* pq = s_esq + kg4;

    #pragma unroll
    for (int t = 0; t < 32; ++t) {
        // all five LDS reads: base + compile-time immediate (ds offset field)
        short8 eh0 = *(const short8*)(ph + o0 + t * 2048);
        short8 eh1 = *(const short8*)(ph + o1 + t * 2048);
        short8 el0 = *(const short8*)(pl + o0 + t * 2048);
        short8 el1 = *(const short8*)(pl + o1 + t * 2048);
        f32x4 eqv  = *(const f32x4*)(pq + t * 16);

        #pragma unroll
        for (int qt = 0; qt < 2; ++qt) {
            // C-init = esq tile; -2 folded into codebook -> acc exits as d2 proxy
            f32x4 acc = eqv;
            acc = __builtin_amdgcn_mfma_f32_16x16x32_bf16(eh0, xh[qt][0], acc, 0, 0, 0);
            acc = __builtin_amdgcn_mfma_f32_16x16x32_bf16(eh1, xh[qt][1], acc, 0, 0, 0);
            acc = __builtin_amdgcn_mfma_f32_16x16x32_bf16(eh0, xl[qt][0], acc, 0, 0, 0);
            acc = __builtin_amdgcn_mfma_f32_16x16x32_bf16(eh1, xl[qt][1], acc, 0, 0, 0);
            acc = __builtin_amdgcn_mfma_f32_16x16x32_bf16(el0, xh[qt][0], acc, 0, 0, 0);
            acc = __builtin_amdgcn_mfma_f32_16x16x32_bf16(el1, xh[qt][1], acc, 0, 0, 0);
            #pragma unroll
            for (int r = 0; r < 4; ++r) {
                float dd = acc[r];
                int   kc = (t * 16) | (kg4 + r);    // disjoint bits, 1 v_or (lit src0)
                bool  lt = dd < m1[qt];
                m2[qt] = lt ? m1[qt] : fminf(m2[qt], dd);
                m1[qt] = lt ? dd : m1[qt];
                i1[qt] = lt ? kc : i1[qt];          // strict < => first index wins
            }
        }
    }

    // combine (m1,i1,m2) across the 4 k-groups holding each query
    #pragma unroll
    for (int qt = 0; qt < 2; ++qt) {
        #pragma unroll
        for (int off = 16; off <= 32; off <<= 1) {
            float om1 = __shfl_xor(m1[qt], off, 64);
            float om2 = __shfl_xor(m2[qt], off, 64);
            int   oi  = __shfl_xor(i1[qt], off, 64);
            bool  lt  = om1 < m1[qt];
            float loser = lt ? m1[qt] : om1;
            m2[qt] = fminf(fminf(m2[qt], om2), loser);
            m1[qt] = lt ? om1 : m1[qt];
            i1[qt] = lt ? oi  : i1[qt];
        }
    }

    // exact fp32 rescan when top-2 gap <= THR >= 2*(bf16x3 bound): fp32 argmin
    // guaranteed; approx ties (gap 0) also land here -> first-index restored.
    #pragma unroll
    for (int qt = 0; qt < 2; ++qt) {
        bool flag = (m2[qt] - m1[qt]) <= THR;
        unsigned long long mask = __ballot(flag && (lane < 16));
        while (mask) {
            int ql = __ffsll(mask) - 1;
            mask &= mask - 1;
            int qf = qw + qt * 16 + ql;                 // wave-uniform
            const float* xq = x + (size_t)qf * D;
            float bb = 3.4e38f;
            int   bq = 0;
            #pragma unroll 1
            for (int c0 = 0; c0 < 8; ++c0) {
                int kc = lane * 8 + c0;
                const float4* ep = (const float4*)(cb + (size_t)kc * D);
                float a = 0.f;
                #pragma unroll
                for (int i = 0; i < 16; ++i) {
                    float4 e = ep[i];
                    a = fmaf(xq[4 * i + 0], e.x, a);
                    a = fmaf(xq[4 * i + 1], e.y, a);
                    a = fmaf(xq[4 * i + 2], e.z, a);
                    a = fmaf(xq[4 * i + 3], e.w, a);
                }
                float dd = fmaf(-2.f, a, s_esq[kc]);
                if (dd < bb) { bb = dd; bq = kc; }      // ascending kc: first index wins
            }
            #pragma unroll
            for (int off = 1; off < 64; off <<= 1) {    // min-reduce, first-index tie-break
                float ob = __shfl_xor(bb, off, 64);
                int   oq = __shfl_xor(bq, off, 64);
                if (ob < bb || (ob == bb && oq < bq)) { bb = ob; bq = oq; }
            }
            if (qrow == ql) i1[qt] = bq;
        }
    }

    // emit: out[q] = cb[i1]; lane (qrow,kg) writes 64 B of query qrow's row
    #pragma unroll
    for (int qt = 0; qt < 2; ++qt) {
        size_t q = (size_t)(qw + qt * 16 + qrow);
        const float4* src = (const float4*)(cb + (size_t)i1[qt] * D) + kg * 4;
        float4*       dst = (float4*)(out + q * D) + kg * 4;
        #pragma unroll
        for (int s = 0; s < 4; ++s) dst[s] = src[s];
    }
}

// ================= SAFE fallback (no ws): round-4 kernel verbatim (proven) =================
__global__ __launch_bounds__(512) void vq_mfma(
        const float* __restrict__ x, const float* __restrict__ cb,
        float* __restrict__ out) {

    __shared__ unsigned short s_e[2][K * D];
    __shared__ float s_esq[K];

    const int tid  = threadIdx.x;
    const int lane = tid & 63;
    const int qrow = lane & 15;
    const int kg   = lane >> 4;
    const int wv   = __builtin_amdgcn_readfirstlane(tid >> 6);
    const int qw   = blockIdx.x * 512 + wv * 64;

    const float4* cbv4 = (const float4*)cb;
    for (int c = tid; c < (K * D) / 4; c += 512) {
        float4 v = cbv4[c];
        float vv[4] = {v.x, v.y, v.z, v.w};
        short4v hi, lo;
        #pragma unroll
        for (int j = 0; j < 4; ++j) {
            unsigned short hb = f2bf(vv[j]);
            hi[j] = (short)hb;
            lo[j] = (short)f2bf(vv[j] - bf2f(hb));
        }
        int byteoff = c * 8;
        int row     = byteoff >> 7;
        int addr    = byteoff ^ ((row & 7) << 4);
        *(short4v*)((char*)s_e[0] + addr) = hi;
        *(short4v*)((char*)s_e[1] + addr) = lo;
    }
    {
        float s = 0.f;
        #pragma unroll
        for (int d = 0; d < D; ++d) {
            float v = cb[tid * D + d];
            s = fmaf(v, v, s);
        }
        s_esq[tid] = s;
    }
    __syncthreads();

    short8 xh[4][2], xl[4][2];
    #pragma unroll
    for (int qt = 0; qt < 4; ++qt) {
        #pragma unroll
        for (int h = 0; h < 2; ++h) {
            const float* p = x + (size_t)(qw + qt * 16 + qrow) * D + h * 32 + kg * 8;
            float4 v0 = *(const float4*)p;
            float4 v1 = *(const float4*)(p + 4);
            float vv[8] = {v0.x, v0.y, v0.z, v0.w, v1.x, v1.y, v1.z, v1.w};
            short8 th, tl;
            #pragma unroll
            for (int j = 0; j < 8; ++j) {
                unsigned short hb = f2bf(vv[j]);
                th[j] = (short)hb;
                tl[j] = (short)f2bf(vv[j] - bf2f(hb));
            }
            xh[qt][h] = th;
            xl[qt][h] = tl;
        }
    }

    float m1[4], m2[4];
    int   i1[4];
    #pragma unroll
    for (int qt = 0; qt < 4; ++qt) { m1[qt] = 3.4e38f; m2[qt] = 3.4e38f; i1[qt] = 0; }

    const f32x4 zacc = {0.f, 0.f, 0.f, 0.f};

    for (int t = 0; t < 32; ++t) {
        const int row  = t * 16 + qrow;
        const int swz  = (row & 7) << 4;
        const int off0 = row * 128 + kg * 16;
        short8 eh0 = *(const short8*)((const char*)s_e[0] + ((off0     ) ^ swz));
        short8 eh1 = *(const short8*)((const char*)s_e[0] + ((off0 + 64) ^ swz));
        short8 el0 = *(const short8*)((const char*)s_e[1] + ((off0     ) ^ swz));
        short8 el1 = *(const short8*)((const char*)s_e[1] + ((off0 + 64) ^ swz));
        f32x4 eq = *(const f32x4*)(s_esq + t * 16 + kg * 4);

        #pragma unroll
        for (int qt = 0; qt < 4; ++qt) {
            f32x4 acc;
            asm volatile(
                "s_nop 3\n\t"
                "v_mfma_f32_16x16x32_bf16 %0, %1, %5, %9\n\t"
                "v_mfma_f32_16x16x32_bf16 %0, %2, %6, %0\n\t"
                "v_mfma_f32_16x16x32_bf16 %0, %1, %7, %0\n\t"
                "v_mfma_f32_16x16x32_bf16 %0, %2, %8, %0\n\t"
                "v_mfma_f32_16x16x32_bf16 %0, %3, %5, %0\n\t"
                "v_mfma_f32_16x16x32_bf16 %0, %4, %6, %0\n\t"
                "s_nop 7\n\t"
                "s_nop 7"
                : "=&v"(acc)
                : "v"(eh0), "v"(eh1), "v"(el0), "v"(el1),
                  "v"(xh[qt][0]), "v"(xh[qt][1]), "v"(xl[qt][0]), "v"(xl[qt][1]),
                  "v"(zacc));
            #pragma unroll
            for (int r = 0; r < 4; ++r) {
                float dd = fmaf(-2.f, acc[r], eq[r]);
                int   kc = t * 16 + kg * 4 + r;
                bool  lt = dd < m1[qt];
                m2[qt] = lt ? m1[qt] : fminf(m2[qt], dd);
                m1[qt] = lt ? dd : m1[qt];
                i1[qt] = lt ? kc : i1[qt];
            }
        }
    }

    #pragma unroll
    for (int qt = 0; qt < 4; ++qt) {
        #pragma unroll
        for (int off = 16; off <= 32; off <<= 1) {
            float om1 = __shfl_xor(m1[qt], off, 64);
            float om2 = __shfl_xor(m2[qt], off, 64);
            int   oi  = __shfl_xor(i1[qt], off, 64);
            bool  lt  = om1 < m1[qt];
            float loser = lt ? m1[qt] : om1;
            m2[qt] = fminf(fminf(m2[qt], om2), loser);
            m1[qt] = lt ? om1 : m1[qt];
            i1[qt] = lt ? oi  : i1[qt];
        }
    }

    #pragma unroll
    for (int qt = 0; qt < 4; ++qt) {
        bool flag = (m2[qt] - m1[qt]) <= 0.008f;
        unsigned long long mask = __ballot(flag && (lane < 16));
        while (mask) {
            int ql = __ffsll(mask) - 1;
            mask &= mask - 1;
            int qf = qw + qt * 16 + ql;
            const float* xq = x + (size_t)qf * D;
            float bb = 3.4e38f;
            int   bq = 0;
            #pragma unroll 1
            for (int c0 = 0; c0 < 8; ++c0) {
                int kc = lane * 8 + c0;
                const float4* ep = (const float4*)(cb + (size_t)kc * D);
                float a = 0.f;
                #pragma unroll
                for (int i = 0; i < 16; ++i) {
                    float4 e = ep[i];
                    a = fmaf(xq[4 * i + 0], e.x, a);
                    a = fmaf(xq[4 * i + 1], e.y, a);
                    a = fmaf(xq[4 * i + 2], e.z, a);
                    a = fmaf(xq[4 * i + 3], e.w, a);
                }
                float dd = fmaf(-2.f, a, s_esq[kc]);
                if (dd < bb) { bb = dd; bq = kc; }
            }
            #pragma unroll
            for (int off = 1; off < 64; off <<= 1) {
                float ob = __shfl_xor(bb, off, 64);
                int   oq = __shfl_xor(bq, off, 64);
                if (ob < bb || (ob == bb && oq < bq)) { bb = ob; bq = oq; }
            }
            if (qrow == ql) i1[qt] = bq;
        }
    }

    #pragma unroll
    for (int qt = 0; qt < 4; ++qt) {
        size_t q = (size_t)(qw + qt * 16 + qrow);
        const float4* src = (const float4*)(cb + (size_t)i1[qt] * D) + kg * 4;
        float4*       dst = (float4*)(out + q * D) + kg * 4;
        #pragma unroll
        for (int s = 0; s < 4; ++s) dst[s] = src[s];
    }
}

extern "C" void kernel_launch(void* const* d_in, const int* in_sizes, int n_in,
                              void* d_out, int out_size, void* d_ws, size_t ws_size,
                              hipStream_t stream) {
    const float* x   = (const float*)d_in[0];   // [8,16384,64]
    const float* cb  = (const float*)d_in[1];   // [512,64]
    float*       out = (float*)d_out;           // [8,16384,1,64]

    const size_t need = 2048 + (size_t)K * D * 2 * 2;   // esq + eh2 + el2 = 133120 B
    if (ws_size >= need) {
        float*          esq = (float*)d_ws;
        unsigned short* eh2 = (unsigned short*)((char*)d_ws + 2048);
        unsigned short* el2 = (unsigned short*)((char*)d_ws + 2048 + K * D * 2);
        prep2_kernel<<<1, 512, 0, stream>>>(cb, esq, eh2, el2);
        vq_mfma7<<<QTOT / 512, 1024, 0, stream>>>(x, cb, esq, eh2, el2, out);
    } else {
        vq_mfma<<<QTOT / 512, 512, 0, stream>>>(x, cb, out);
    }
}